// Round 2
// baseline (94.936 us; speedup 1.0000x reference)
//
#include <hip/hip_runtime.h>

#define IN_CH 16
#define OUT_CH 32
#define NUM_INPUTS 144   // IN_CH * 3 * 3
#define BATCH 8
#define H_ 32
#define W_ 32
#define TILE_H 8
#define LDS_H 10         // TILE_H + 2 halo
#define LDS_W 34         // W + 2 halo; 34 mod 32 == 2 -> 2 lanes/bank (free)

// ---------------------------------------------------------------------------
// Prep: per (i,o) pair, segment params for
//   y(p) = m0*p + b0 + (m1-m0)*max(p - pos1, 0)
// tab[idx] = (p1, m0, m1-m0, b0).  4608 pairs = 18 blocks x 256, one each.
// No atomics, no reductions (b0 is reduced per-block in apc_main).
// ---------------------------------------------------------------------------
__global__ void apc_prep(const float* __restrict__ pos,
                         const float* __restrict__ val,
                         float4* __restrict__ tab) {
    int idx = blockIdx.x * 256 + threadIdx.x;        // exactly 4608 threads
    const float* pp = pos + idx * 3;
    const float* vv = val + idx * 3;
    float p0 = pp[0], p1 = pp[1], p2 = pp[2];
    float v0 = vv[0], v1 = vv[1], v2 = vv[2];
    float m0 = (v1 - v0) / (p1 - p0);
    float m1 = (v2 - v1) / (p2 - p1);
    tab[idx] = make_float4(p1, m0, m1 - m0, v0 - m0 * p0);
}

// ---------------------------------------------------------------------------
// Main: grid (32 spatial tiles, 16 o-groups), block 256.
// Block = one image's 8x32 output rows x 2 output channels.
// Phase 0: stage 16ch x 10x34 zero-padded x tile in LDS; waves 0/1 reduce
//          b0sum for the block's 2 channels (shuffle reduce, no atomics).
// Phase 1: fully-unrolled 144-tap loop; table reads are wave-uniform ->
//          scalar loads (t0/t1 adjacent -> s_load_dwordx8); patch reads are
//          LDS conflict-free (stride 34 == 2 mod 32 -> 2 lanes/bank).
// ---------------------------------------------------------------------------
__global__ __launch_bounds__(256, 2) void apc_main(
        const float* __restrict__ x,
        const float4* __restrict__ tab,
        float* __restrict__ out) {
    __shared__ float lx[IN_CH * LDS_H * LDS_W];
    __shared__ float b0s[2];

    int bx  = blockIdx.x;          // 0..31: b*4 + row_tile
    int b   = bx >> 2;
    int ho0 = (bx & 3) * TILE_H;
    int tid = threadIdx.x;
    int o0  = blockIdx.y * 2;      // 2 output channels per block

    // Stage x tile with zero-padded halo.
    for (int idx = tid; idx < IN_CH * LDS_H * LDS_W; idx += 256) {
        int c   = idx / (LDS_H * LDS_W);
        int rem = idx - c * (LDS_H * LDS_W);
        int r   = rem / LDS_W;
        int col = rem - r * LDS_W;
        int gr  = ho0 + r - 1;
        int gc  = col - 1;
        float v = 0.f;
        if ((unsigned)gr < (unsigned)H_ && (unsigned)gc < (unsigned)W_)
            v = x[((b * IN_CH + c) * H_ + gr) * W_ + gc];
        lx[idx] = v;
    }

    // Waves 0/1: reduce b0sum for channel o0+wave (144 values each).
    int wave = tid >> 6, lane = tid & 63;
    if (wave < 2) {
        int o = o0 + wave;
        float s = 0.f;
        for (int i = lane; i < NUM_INPUTS; i += 64)
            s += tab[i * OUT_CH + o].w;
        #pragma unroll
        for (int off = 32; off; off >>= 1)
            s += __shfl_down(s, off);
        if (lane == 0) b0s[wave] = s;
    }
    __syncthreads();

    int rl    = tid >> 5;          // 0..7 local output row
    int col   = tid & 31;          // output col
    int baseA = rl * LDS_W + col;

    float a0 = b0s[0], h0 = 0.f;   // split chains: sum m0*p  and  sum dm*relu
    float a1 = b0s[1], h1 = 0.f;

    #pragma unroll
    for (int c = 0; c < IN_CH; ++c) {
        #pragma unroll
        for (int kh = 0; kh < 3; ++kh) {
            #pragma unroll
            for (int kw = 0; kw < 3; ++kw) {
                int i = (c * 3 + kh) * 3 + kw;          // (c, kh, kw) ordering
                float p = lx[c * (LDS_H * LDS_W) + kh * LDS_W + kw + baseA];
                float4 t0 = tab[i * OUT_CH + o0];
                float4 t1 = tab[i * OUT_CH + o0 + 1];
                a0 = fmaf(t0.y, p, a0);
                h0 = fmaf(t0.z, fmaxf(p - t0.x, 0.f), h0);
                a1 = fmaf(t1.y, p, a1);
                h1 = fmaf(t1.z, fmaxf(p - t1.x, 0.f), h1);
            }
        }
    }

    int ho = ho0 + rl;
    out[((b * OUT_CH + o0    ) * H_ + ho) * W_ + col] = a0 + h0;
    out[((b * OUT_CH + o0 + 1) * H_ + ho) * W_ + col] = a1 + h1;
}

extern "C" void kernel_launch(void* const* d_in, const int* in_sizes, int n_in,
                              void* d_out, int out_size, void* d_ws, size_t ws_size,
                              hipStream_t stream) {
    const float* x   = (const float*)d_in[0];
    const float* pos = (const float*)d_in[1];
    const float* val = (const float*)d_in[2];

    float4* tab = (float4*)d_ws;   // 4608 * 16 B = 73728 B

    apc_prep<<<18, 256, 0, stream>>>(pos, val, tab);

    dim3 grid(32, 16);
    // DIAGNOSTIC (this round only): launch main twice. Work is idempotent, so
    // output is identical; the dur_us delta vs round 1 measures main's true
    // per-launch cost, which top-5 rocprof hides below the 40us poison fills.
    apc_main<<<grid, 256, 0, stream>>>(x, tab, (float*)d_out);
    apc_main<<<grid, 256, 0, stream>>>(x, tab, (float*)d_out);
}

// Round 3
// 77.547 us; speedup vs baseline: 1.2242x; 1.2242x over previous
//
#include <hip/hip_runtime.h>

#define IN_CH 16
#define OUT_CH 32
#define NUM_INPUTS 144   // IN_CH * 3 * 3
#define H_ 32
#define W_ 32
#define TILE_H 8
#define LDS_H 10         // TILE_H + 2 halo
#define LDS_W 34         // W + 2 halo; 34 mod 32 == 2 -> 2 lanes/bank (free)
#define CSPLIT 8         // input channels per split-K block
#define TAPS (CSPLIT*9)  // 72

typedef __attribute__((ext_vector_type(2))) float f32x2;

// ---------------------------------------------------------------------------
// Prep: per (i,o) pair, params of y(p) = m0*p + b0 + (m1-m0)*max(p-p1, 0)
// (continuous at p1, so it reproduces both clipped extrapolation tails).
// SoA float2 channel-pair layout so the main kernel's wave-uniform reads are
// s_load_dwordx2/x4: tabX[i*16 + pair], halves = channels 2*pair, 2*pair+1.
// ---------------------------------------------------------------------------
__global__ void apc_prep(const float* __restrict__ pos,
                         const float* __restrict__ val,
                         float* __restrict__ tabP, float* __restrict__ tabM,
                         float* __restrict__ tabD, float* __restrict__ tabB) {
    int e = blockIdx.x * 256 + threadIdx.x;   // 0..4607 = i*32 + o
    const float* pp = pos + e * 3;
    const float* vv = val + e * 3;
    float p0 = pp[0], p1 = pp[1], p2 = pp[2];
    float v0 = vv[0], v1 = vv[1], v2 = vv[2];
    float m0 = (v1 - v0) / (p1 - p0);
    float m1 = (v2 - v1) / (p2 - p1);
    // e = i*32 + o ; flat float2-half index is identical to e itself:
    // (i*16 + (o>>1)) * 2 + (o&1) == i*32 + o.  Write scalars directly.
    tabP[e] = p1;
    tabM[e] = m0;
    tabD[e] = m1 - m0;
    tabB[e] = v0 - m0 * p0;
}

// ---------------------------------------------------------------------------
// Main: grid (32 spatial tiles, 8 channel-quads, 2 c-splits), block 256.
// Block = one image's 8x32 output rows x 4 output channels x 8 input chans.
// Phase 0: stage 8ch x 10x34 zero-padded x tile in LDS (10.9 KB); waves 0/1
//          reduce this split's b0 sums for the 2 channel-pairs.
// Phase 1: fully-unrolled 72-tap loop, float2 packed math per channel-pair
//          (v_pk_fma_f32 / v_pk_max_f32); table reads wave-uniform -> s_load.
//          Patch reads conflict-free (stride 34 == 2 mod 32 -> 2 lanes/bank).
// Epilogue: atomicAdd partials into memset-zeroed out (split-K combine).
// ---------------------------------------------------------------------------
__global__ __launch_bounds__(256, 2) void apc_main(
        const float* __restrict__ x,
        const f32x2* __restrict__ tabP, const f32x2* __restrict__ tabM,
        const f32x2* __restrict__ tabD, const f32x2* __restrict__ tabB,
        float* __restrict__ out) {
    __shared__ float lx[CSPLIT * LDS_H * LDS_W];
    __shared__ f32x2 b0s[2];

    int bx  = blockIdx.x;            // 0..31: b*4 + row_tile
    int b   = bx >> 2;
    int ho0 = (bx & 3) * TILE_H;
    int pr0 = blockIdx.y * 2;        // channel-pair base; o0 = pr0*2
    int c0  = blockIdx.z * CSPLIT;   // input-channel split
    int tid = threadIdx.x;
    int i0  = c0 * 9;                // first tap index of this split

    // Stage x tile with zero-padded halo (2720 floats, 11 strided iters).
    for (int idx = tid; idx < CSPLIT * LDS_H * LDS_W; idx += 256) {
        int c   = idx / (LDS_H * LDS_W);
        int rem = idx - c * (LDS_H * LDS_W);
        int r   = rem / LDS_W;
        int col = rem - r * LDS_W;
        int gr  = ho0 + r - 1;
        int gc  = col - 1;
        float v = 0.f;
        if ((unsigned)gr < (unsigned)H_ && (unsigned)gc < (unsigned)W_)
            v = x[((b * IN_CH + c0 + c) * H_ + gr) * W_ + gc];
        lx[idx] = v;
    }

    // Waves 0/1: reduce b0 over this split's 72 taps for pair pr0+wave.
    int wave = tid >> 6, lane = tid & 63;
    if (wave < 2) {
        f32x2 s = {0.f, 0.f};
        for (int t = lane; t < TAPS; t += 64)
            s += tabB[(i0 + t) * 16 + pr0 + wave];
        #pragma unroll
        for (int off = 32; off; off >>= 1) {
            s.x += __shfl_down(s.x, off);
            s.y += __shfl_down(s.y, off);
        }
        if (lane == 0) b0s[wave] = s;
    }
    __syncthreads();

    int rl    = tid >> 5;            // 0..7 local output row
    int col   = tid & 31;            // output col
    int baseA = rl * LDS_W + col;

    f32x2 a0 = {0.f, 0.f}, h0 = {0.f, 0.f};   // pair (o0, o0+1)
    f32x2 a1 = {0.f, 0.f}, h1 = {0.f, 0.f};   // pair (o0+2, o0+3)
    const f32x2 zz = {0.f, 0.f};

    #pragma unroll
    for (int c = 0; c < CSPLIT; ++c) {
        #pragma unroll
        for (int kh = 0; kh < 3; ++kh) {
            #pragma unroll
            for (int kw = 0; kw < 3; ++kw) {
                int t  = (c * 3 + kh) * 3 + kw;
                int ti = (i0 + t) * 16;
                float p = lx[c * (LDS_H * LDS_W) + kh * LDS_W + kw + baseA];
                f32x2 pb = {p, p};
                f32x2 P0 = tabP[ti + pr0], P1 = tabP[ti + pr0 + 1];
                f32x2 M0 = tabM[ti + pr0], M1 = tabM[ti + pr0 + 1];
                f32x2 D0 = tabD[ti + pr0], D1 = tabD[ti + pr0 + 1];
                f32x2 r0 = __builtin_elementwise_max(pb - P0, zz);
                f32x2 r1 = __builtin_elementwise_max(pb - P1, zz);
                a0 = __builtin_elementwise_fma(M0, pb, a0);
                a1 = __builtin_elementwise_fma(M1, pb, a1);
                h0 = __builtin_elementwise_fma(D0, r0, h0);
                h1 = __builtin_elementwise_fma(D1, r1, h1);
            }
        }
    }

    a0 += h0 + b0s[0];
    a1 += h1 + b0s[1];

    int ho = ho0 + rl;
    int o0 = pr0 * 2;
    int ob = ((b * OUT_CH + o0) * H_ + ho) * W_ + col;
    atomicAdd(&out[ob            ], a0.x);
    atomicAdd(&out[ob +     H_*W_], a0.y);
    atomicAdd(&out[ob + 2 * H_*W_], a1.x);
    atomicAdd(&out[ob + 3 * H_*W_], a1.y);
}

extern "C" void kernel_launch(void* const* d_in, const int* in_sizes, int n_in,
                              void* d_out, int out_size, void* d_ws, size_t ws_size,
                              hipStream_t stream) {
    const float* x   = (const float*)d_in[0];
    const float* pos = (const float*)d_in[1];
    const float* val = (const float*)d_in[2];

    // SoA tables in workspace: 4 arrays x 4608 float2 = 36864 B each.
    char* w = (char*)d_ws;
    float* tabP = (float*)(w);
    float* tabM = (float*)(w + 36864);
    float* tabD = (float*)(w + 73728);
    float* tabB = (float*)(w + 110592);

    // d_out is poisoned 0xAA before every timed call; zero it for the
    // split-K atomic combine (async memset is graph-capturable).
    hipMemsetAsync(d_out, 0, (size_t)out_size * sizeof(float), stream);

    apc_prep<<<18, 256, 0, stream>>>(pos, val, tabP, tabM, tabD, tabB);

    dim3 grid(32, 8, 2);
    apc_main<<<grid, 256, 0, stream>>>(x, (const f32x2*)tabP, (const f32x2*)tabM,
                                       (const f32x2*)tabD, (const f32x2*)tabB,
                                       (float*)d_out);
}